// Round 15
// baseline (35.901 us; speedup 1.0000x reference)
//
#include <hip/hip_runtime.h>
#include <math.h>

namespace {

constexpr int K = 256, D = 256, P = 40, C = 32;
constexpr int LN = 2048;     // LUT intervals over s in [-1,1]
constexpr int NOUT = K * K;  // 65536
constexpr int LB = (LN + 1 + 255) / 256;  // LUT blocks
constexpr int CZB = 4;                    // corr-zero blocks (4 x 64 KB)

typedef __attribute__((ext_vector_type(8))) short bf16x8;
typedef __attribute__((ext_vector_type(4))) float f32x4;

__device__ __forceinline__ float tanh_fast(float x) {
  float e = __expf(2.0f * x);
  return 1.0f - __fdividef(2.0f, e + 1.0f);
}

// round-to-nearest bf16 split: (hi16) | (lo16 << 16); hi+lo ~ v to ~2^-18 rel
__device__ __forceinline__ unsigned bf16pair(float v) {
  unsigned u = __float_as_uint(v);
  unsigned hi = (u + 0x7fffu + ((u >> 16) & 1u)) >> 16;
  float lo = v - __uint_as_float(hi << 16);
  unsigned ul = __float_as_uint(lo);
  unsigned lo16 = (ul + 0x7fffu + ((ul >> 16) & 1u)) >> 16;
  return hi | (lo16 << 16);
}

__device__ __forceinline__ void gload16(const void* g, void* l) {
  __builtin_amdgcn_global_load_lds((const __attribute__((address_space(1))) void*)g,
                                   (__attribute__((address_space(3))) void*)l, 16, 0, 0);
}

// ---- prep (+ merged init): blocks [0,2K): register-resident L2-norm + transpose
//      + bf16-split (no LDS tile, shfl-reduce norms); then LUT / corr-zero / pw ----
__global__ __launch_bounds__(256) void kprep(const float* __restrict__ e,
                                             const float* __restrict__ ts,
                                             const float* __restrict__ fc1w,
                                             const float* __restrict__ fc1b,
                                             const float* __restrict__ fc2w,
                                             const float* __restrict__ pho_w,
                                             unsigned* __restrict__ Ep,
                                             unsigned* __restrict__ Tp,
                                             float* __restrict__ tab,
                                             float* __restrict__ corr,
                                             float* __restrict__ pwv) {
  const int bid = blockIdx.x;
  const int t = threadIdx.x;
  if (bid >= 2 * K) {
    int ib = bid - 2 * K;
    if (ib < LB) {
      int i = ib * 256 + t;
      if (i <= LN) {
        float s = -1.0f + (float)i * (2.0f / LN);
        float g = 0.f;
#pragma unroll
        for (int c = 0; c < C; ++c) g = fmaf(tanh_fast(fmaf(s, fc1w[c], fc1b[c])), fc2w[c], g);
        tab[i] = tanh_fast(g * s);
      }
      return;
    }
    ib -= LB;
    if (ib < CZB) {  // zero the 256 KB corr plane
      float4* cz = (float4*)corr + (size_t)ib * (256 * 16);
#pragma unroll
      for (int i = 0; i < 16; ++i) cz[i * 256 + t] = make_float4(0.f, 0.f, 0.f, 0.f);
      return;
    }
    // pw block: pwv[0..P) normalized weights, pwv[P] = sum
    float wmin = pho_w[0], wmax = pho_w[0];
    for (int i = 1; i < P; ++i) {
      float v = pho_w[i];
      wmin = fminf(wmin, v);
      wmax = fmaxf(wmax, v);
    }
    float inv = 1.0f / (1e-6f + wmax - wmin);
    if (t < P) pwv[t] = (pho_w[t] - wmin) * inv;
    if (t == 64) {
      float sum = 0.f;
      for (int i = 0; i < P; ++i) sum += (pho_w[i] - wmin) * inv;
      pwv[P] = sum;
    }
    return;
  }
  // ---- prep path: thread t owns d-row t (40 floats, contiguous 160 B) ----
  __shared__ float wred[4 * P];  // per-wave partial sums
  __shared__ float inv[P];
  const float* x = (bid < K) ? e : ts;
  unsigned* xt = (bid < K) ? Ep : Tp;
  const int a = bid & (K - 1);
  const int lane = t & 63, w = t >> 6;

  float4 v[10];
  const float4* row4 = (const float4*)(x + ((size_t)a * D + t) * P);
#pragma unroll
  for (int k = 0; k < 10; ++k) v[k] = row4[k];

  // per-p square + 64-lane butterfly reduce (sum over the wave's 64 d values)
  float ss[P];
#pragma unroll
  for (int k = 0; k < 10; ++k) {
    ss[4 * k + 0] = v[k].x * v[k].x;
    ss[4 * k + 1] = v[k].y * v[k].y;
    ss[4 * k + 2] = v[k].z * v[k].z;
    ss[4 * k + 3] = v[k].w * v[k].w;
  }
#pragma unroll
  for (int p = 0; p < P; ++p) {
    float s = ss[p];
#pragma unroll
    for (int m = 1; m < 64; m <<= 1) s += __shfl_xor(s, m);
    ss[p] = s;
  }
  if (lane == 0) {
#pragma unroll
    for (int p = 0; p < P; ++p) wred[w * P + p] = ss[p];
  }
  __syncthreads();
  if (t < P) {
    float tot = wred[t] + wred[P + t] + wred[2 * P + t] + wred[3 * P + t];
    inv[t] = 1.0f / fmaxf(sqrtf(tot), 1e-12f);
  }
  __syncthreads();

  // write: for each p, wave writes 64 consecutive u32 (256 B, coalesced)
#pragma unroll
  for (int k = 0; k < 10; ++k) {
    xt[(((size_t)(4 * k + 0) * K + a) << 8) + t] = bf16pair(v[k].x * inv[4 * k + 0]);
    xt[(((size_t)(4 * k + 1) * K + a) << 8) + t] = bf16pair(v[k].y * inv[4 * k + 1]);
    xt[(((size_t)(4 * k + 2) * K + a) << 8) + t] = bf16pair(v[k].z * inv[4 * k + 2]);
    xt[(((size_t)(4 * k + 3) * K + a) << 8) + t] = bf16pair(v[k].w * inv[4 * k + 3]);
  }
}

// ---- kgemm: 640 blocks = 16 (64x64) tiles x 40 p; BK=64 double-buffered
//      (counted vmcnt(4)), 32 KB LDS -> 5 blocks/CU (unchanged from R14) ----
__global__ __launch_bounds__(256) void kgemm(const unsigned* __restrict__ Ep,
                                             const unsigned* __restrict__ Tp,
                                             const float* __restrict__ tab,
                                             const float* __restrict__ pwv,
                                             float* __restrict__ part,
                                             float* __restrict__ corr) {
  __shared__ __align__(16) char Buf[2][16 * 1024];  // [buf][A 8KB | B 8KB]
  const int id = blockIdx.x;
  const int tile = id & 15;  // 4x4 tiles of 64x64
  const int p = id >> 4;
  const int a0 = (tile >> 2) * 64, b0 = (tile & 3) * 64;
  const int t = threadIdx.x, lane = t & 63, w = t >> 6;

  // staging: waves 0,1 -> A rows 0..63; waves 2,3 -> B rows 0..63 (128 B/row/step)
  const bool isB = (w >= 2);
  const char* panel = (isB ? (const char*)Tp : (const char*)Ep) + (size_t)p * (K * 1024) +
                      (size_t)(isB ? b0 : a0) * 1024;
  const int wrow0 = (w & 1) * 32;
  const int lrow = lane >> 3, lcol = (lane & 7) << 4;
  const int dofs = isB ? 8 * 1024 : 0;

  auto stage = [&](char* buf, int ks) {
    char* dst = buf + dofs;
#pragma unroll
    for (int i = 0; i < 4; ++i) {
      const int row = wrow0 + i * 8 + lrow;
      gload16(panel + (size_t)row * 1024 + ks * 128 + (lcol ^ ((row & 7) << 4)),
              dst + row * 128 + lcol);
    }
  };

  const float pwp = pwv[p];  // uniform s_load, no vmcnt traffic

  stage(Buf[0], 0);  // prologue: 4 loads in flight per wave

  // compute geometry: wave w owns 32x32 quadrant (qr, qc); 2x2 frags of 16x16
  const int qr = (w >> 1) * 32, qc = (w & 1) * 32;
  const int l15 = lane & 15, hi16 = (lane >> 4) * 16;
  const int rsw = (l15 & 7) << 4;

  f32x4 acc00 = {0.f, 0.f, 0.f, 0.f}, acc01 = acc00, acc10 = acc00, acc11 = acc00;

#pragma unroll
  for (int ks = 0; ks < 8; ++ks) {
    const int cur = ks & 1;
    if (ks < 7) {
      stage(Buf[cur ^ 1], ks + 1);                      // 4 more in flight
      asm volatile("s_waitcnt vmcnt(4)" ::: "memory");  // current buf's 4 done
    } else {
      asm volatile("s_waitcnt vmcnt(0)" ::: "memory");
    }
    __builtin_amdgcn_s_barrier();
    __builtin_amdgcn_sched_barrier(0);
    const char* Ar0 = Buf[cur] + (size_t)(qr + l15) * 128;
    const char* Ar1 = Buf[cur] + (size_t)(qr + 16 + l15) * 128;
    const char* Br0 = Buf[cur] + 8 * 1024 + (size_t)(qc + l15) * 128;
    const char* Br1 = Buf[cur] + 8 * 1024 + (size_t)(qc + 16 + l15) * 128;
    __builtin_amdgcn_s_setprio(1);
#pragma unroll
    for (int kk = 0; kk < 2; ++kk) {
      const int off = (kk * 64 + hi16) ^ rsw;
      bf16x8 af0 = *(const bf16x8*)(Ar0 + off);
      bf16x8 af1 = *(const bf16x8*)(Ar1 + off);
      bf16x8 bf0 = *(const bf16x8*)(Br0 + off);
      bf16x8 bf1 = *(const bf16x8*)(Br1 + off);
      acc00 = __builtin_amdgcn_mfma_f32_16x16x32_bf16(af0, bf0, acc00, 0, 0, 0);
      acc01 = __builtin_amdgcn_mfma_f32_16x16x32_bf16(af0, bf1, acc01, 0, 0, 0);
      acc10 = __builtin_amdgcn_mfma_f32_16x16x32_bf16(af1, bf0, acc10, 0, 0, 0);
      acc11 = __builtin_amdgcn_mfma_f32_16x16x32_bf16(af1, bf1, acc11, 0, 0, 0);
    }
    __builtin_amdgcn_s_setprio(0);
    __builtin_amdgcn_s_barrier();  // reads of Buf[cur] done before it is re-staged
    __builtin_amdgcn_sched_barrier(0);
  }

  // epilogue: F(s) via L2 LUT (8 KB, hot), weighted, non-atomic write to p's plane
  float* pp = part + (size_t)p * NOUT;
  const int ar = a0 + qr + (lane >> 4) * 4;
  const int bc = b0 + qc + l15;
#pragma unroll
  for (int j = 0; j < 4; ++j) {
    float sv[4] = {acc00[j], acc01[j], acc10[j], acc11[j]};
    int id4[4] = {(ar + j) * K + bc, (ar + j) * K + bc + 16,
                  (ar + 16 + j) * K + bc, (ar + 16 + j) * K + bc + 16};
#pragma unroll
    for (int q = 0; q < 4; ++q) {
      float s = sv[q];
      float u = fminf(fmaxf((s + 1.0f) * (LN / 2), 0.0f), (float)LN);
      int i = min((int)u, LN - 1);
      float lt0 = tab[i], lt1 = tab[i + 1];
      float F = fmaf(u - (float)i, lt1 - lt0, lt0);
      pp[id4[q]] = F * pwp;
      if (s == 0.0f) atomicAdd(&corr[id4[q]], pwp);  // never taken on real data
    }
  }
}

// ---- finalize: reduce 40 p planes, divide ----
__global__ __launch_bounds__(256) void kdiv(const float* __restrict__ part,
                                            const float* __restrict__ corr,
                                            const float* __restrict__ pwv,
                                            float* __restrict__ out) {
  int gi = blockIdx.x * 256 + threadIdx.x;
  float s = 0.f;
#pragma unroll
  for (int p = 0; p < P; ++p) s += part[(size_t)p * NOUT + gi];
  out[gi] = s / (pwv[P] - corr[gi] + 1e-6f);
}

// ---- emergency fallback (no workspace needed) ----
__global__ __launch_bounds__(256) void kmono(const float* __restrict__ enroll,
                                             const float* __restrict__ test,
                                             const float* __restrict__ pho_w,
                                             const float* __restrict__ fc1w,
                                             const float* __restrict__ fc1b,
                                             const float* __restrict__ fc2w,
                                             float* __restrict__ out) {
  __shared__ float w1[C], b1[C], w2[C], pwm[P];
  const int t = threadIdx.x;
  if (t < C) {
    w1[t] = fc1w[t];
    b1[t] = fc1b[t];
    w2[t] = fc2w[t];
  }
  if (t < P) {
    float wmin = pho_w[0], wmax = pho_w[0];
    for (int i = 1; i < P; ++i) {
      float v = pho_w[i];
      wmin = fminf(wmin, v);
      wmax = fmaxf(wmax, v);
    }
    pwm[t] = (pho_w[t] - wmin) / (1e-6f + wmax - wmin);
  }
  __syncthreads();
  const int idx = blockIdx.x * 256 + t;
  const int a = idx >> 8, b = idx & 255;
  float score = 0.f, nz = 0.f;
  for (int p = 0; p < P; ++p) {
    float se = 0.f, st = 0.f, dot = 0.f;
    for (int d = 0; d < D; ++d) {
      float ev = enroll[((size_t)a * D + d) * P + p];
      float tv = test[((size_t)b * D + d) * P + p];
      se = fmaf(ev, ev, se);
      st = fmaf(tv, tv, st);
      dot = fmaf(ev, tv, dot);
    }
    float s = dot * (1.0f / fmaxf(sqrtf(se), 1e-12f)) * (1.0f / fmaxf(sqrtf(st), 1e-12f));
    float g = 0.f;
#pragma unroll
    for (int c = 0; c < C; ++c) g = fmaf(tanh_fast(fmaf(s, w1[c], b1[c])), w2[c], g);
    float f = tanh_fast(g * s);
    score = fmaf(f, pwm[p], score);
    if (s != 0.0f) nz += pwm[p];
  }
  out[idx] = score / (nz + 1e-6f);
}

}  // namespace

extern "C" void kernel_launch(void* const* d_in, const int* in_sizes, int n_in,
                              void* d_out, int out_size, void* d_ws, size_t ws_size,
                              hipStream_t stream) {
  const float* enroll = (const float*)d_in[0];
  const float* test = (const float*)d_in[1];
  const float* pho_w = (const float*)d_in[2];
  const float* fc1w = (const float*)d_in[3];
  const float* fc1b = (const float*)d_in[4];
  const float* fc2w = (const float*)d_in[5];
  float* out = (float*)d_out;

  const size_t sz_pair = (size_t)P * K * 256 * sizeof(unsigned);  // 10.49 MB each
  const size_t need = 2 * sz_pair + (size_t)P * NOUT * sizeof(float) +
                      (size_t)NOUT * sizeof(float) + (size_t)(LN + 8) * sizeof(float) +
                      (size_t)(P + 1) * sizeof(float);
  if (ws_size >= need) {
    unsigned* Ep = (unsigned*)d_ws;
    unsigned* Tp = Ep + sz_pair / 4;
    float* part = (float*)(Tp + sz_pair / 4);  // [40][NOUT]
    float* corr = part + (size_t)P * NOUT;     // [NOUT]
    float* tab = corr + NOUT;
    float* pwv = tab + (LN + 4);

    kprep<<<2 * K + LB + CZB + 1, 256, 0, stream>>>(enroll, test, fc1w, fc1b, fc2w, pho_w,
                                                    Ep, Tp, tab, corr, pwv);
    kgemm<<<16 * P, 256, 0, stream>>>(Ep, Tp, tab, pwv, part, corr);
    kdiv<<<NOUT / 256, 256, 0, stream>>>(part, corr, pwv, out);
  } else {
    kmono<<<(K * K) / 256, 256, 0, stream>>>(enroll, test, pho_w, fc1w, fc1b, fc2w, out);
  }
}

// Round 17
// 29.410 us; speedup vs baseline: 1.2207x; 1.2207x over previous
//
#include <hip/hip_runtime.h>
#include <math.h>

namespace {

constexpr int K = 256, D = 256, P = 40, C = 32;
constexpr int LN = 2048;     // LUT intervals over s in [-1,1]
constexpr int NOUT = K * K;  // 65536
constexpr int LB = (LN + 1 + 255) / 256;  // LUT blocks
constexpr int CZB = 4;                    // corr-zero blocks (4 x 64 KB)

typedef __attribute__((ext_vector_type(8))) short bf16x8;
typedef __attribute__((ext_vector_type(4))) float f32x4;

__device__ __forceinline__ float tanh_fast(float x) {
  float e = __expf(2.0f * x);
  return 1.0f - __fdividef(2.0f, e + 1.0f);
}

// round-to-nearest-even bf16
__device__ __forceinline__ unsigned short bf16rn(float v) {
  unsigned u = __float_as_uint(v);
  return (unsigned short)((u + 0x7fffu + ((u >> 16) & 1u)) >> 16);
}

__device__ __forceinline__ void gload16(const void* g, void* l) {
  __builtin_amdgcn_global_load_lds((const __attribute__((address_space(1))) void*)g,
                                   (__attribute__((address_space(3))) void*)l, 16, 0, 0);
}

// ---- prep (+ merged init): blocks [0,2K): register-resident L2-norm + transpose
//      + bf16 cast (hi only); then LUT / corr-zero / pw blocks ----
__global__ __launch_bounds__(256) void kprep(const float* __restrict__ e,
                                             const float* __restrict__ ts,
                                             const float* __restrict__ fc1w,
                                             const float* __restrict__ fc1b,
                                             const float* __restrict__ fc2w,
                                             const float* __restrict__ pho_w,
                                             unsigned short* __restrict__ Ep,
                                             unsigned short* __restrict__ Tp,
                                             float* __restrict__ tab,
                                             float* __restrict__ corr,
                                             float* __restrict__ pwv) {
  const int bid = blockIdx.x;
  const int t = threadIdx.x;
  if (bid >= 2 * K) {
    int ib = bid - 2 * K;
    if (ib < LB) {
      int i = ib * 256 + t;
      if (i <= LN) {
        float s = -1.0f + (float)i * (2.0f / LN);
        float g = 0.f;
#pragma unroll
        for (int c = 0; c < C; ++c) g = fmaf(tanh_fast(fmaf(s, fc1w[c], fc1b[c])), fc2w[c], g);
        tab[i] = tanh_fast(g * s);
      }
      return;
    }
    ib -= LB;
    if (ib < CZB) {  // zero the 256 KB corr plane
      float4* cz = (float4*)corr + (size_t)ib * (256 * 16);
#pragma unroll
      for (int i = 0; i < 16; ++i) cz[i * 256 + t] = make_float4(0.f, 0.f, 0.f, 0.f);
      return;
    }
    // pw block: pwv[0..P) normalized weights, pwv[P] = sum
    float wmin = pho_w[0], wmax = pho_w[0];
    for (int i = 1; i < P; ++i) {
      float v = pho_w[i];
      wmin = fminf(wmin, v);
      wmax = fmaxf(wmax, v);
    }
    float inv = 1.0f / (1e-6f + wmax - wmin);
    if (t < P) pwv[t] = (pho_w[t] - wmin) * inv;
    if (t == 64) {
      float sum = 0.f;
      for (int i = 0; i < P; ++i) sum += (pho_w[i] - wmin) * inv;
      pwv[P] = sum;
    }
    return;
  }
  // ---- prep path: thread t owns d-row t (40 floats, contiguous 160 B) ----
  __shared__ float wred[4 * P];  // per-wave partial sums
  __shared__ float inv[P];
  const float* x = (bid < K) ? e : ts;
  unsigned short* xt = (bid < K) ? Ep : Tp;
  const int a = bid & (K - 1);
  const int lane = t & 63, w = t >> 6;

  float4 v[10];
  const float4* row4 = (const float4*)(x + ((size_t)a * D + t) * P);
#pragma unroll
  for (int k = 0; k < 10; ++k) v[k] = row4[k];

  // per-p square + 64-lane butterfly reduce (sum over the wave's 64 d values)
  float ss[P];
#pragma unroll
  for (int k = 0; k < 10; ++k) {
    ss[4 * k + 0] = v[k].x * v[k].x;
    ss[4 * k + 1] = v[k].y * v[k].y;
    ss[4 * k + 2] = v[k].z * v[k].z;
    ss[4 * k + 3] = v[k].w * v[k].w;
  }
#pragma unroll
  for (int p = 0; p < P; ++p) {
    float s = ss[p];
#pragma unroll
    for (int m = 1; m < 64; m <<= 1) s += __shfl_xor(s, m);
    ss[p] = s;
  }
  if (lane == 0) {
#pragma unroll
    for (int p = 0; p < P; ++p) wred[w * P + p] = ss[p];
  }
  __syncthreads();
  if (t < P) {
    float tot = wred[t] + wred[P + t] + wred[2 * P + t] + wred[3 * P + t];
    inv[t] = 1.0f / fmaxf(sqrtf(tot), 1e-12f);
  }
  __syncthreads();

  // write: for each p, wave writes 64 consecutive bf16 (128 B, coalesced)
#pragma unroll
  for (int k = 0; k < 10; ++k) {
    xt[(((size_t)(4 * k + 0) * K + a) << 8) + t] = bf16rn(v[k].x * inv[4 * k + 0]);
    xt[(((size_t)(4 * k + 1) * K + a) << 8) + t] = bf16rn(v[k].y * inv[4 * k + 1]);
    xt[(((size_t)(4 * k + 2) * K + a) << 8) + t] = bf16rn(v[k].z * inv[4 * k + 2]);
    xt[(((size_t)(4 * k + 3) * K + a) << 8) + t] = bf16rn(v[k].w * inv[4 * k + 3]);
  }
}

// ---- kgemm: 640 blocks = 16 (64x64) tiles x 40 p; K=256 bf16, BK=64, 4 steps,
//      double-buffered (counted vmcnt(4)), 32 KB LDS -> 5 blocks/CU ----
__global__ __launch_bounds__(256) void kgemm(const unsigned short* __restrict__ Ep,
                                             const unsigned short* __restrict__ Tp,
                                             const float* __restrict__ tab,
                                             const float* __restrict__ pwv,
                                             float* __restrict__ part,
                                             float* __restrict__ corr) {
  __shared__ __align__(16) char Buf[2][16 * 1024];  // [buf][A 8KB | B 8KB]
  const int id = blockIdx.x;
  const int tile = id & 15;  // 4x4 tiles of 64x64
  const int p = id >> 4;
  const int a0 = (tile >> 2) * 64, b0 = (tile & 3) * 64;
  const int t = threadIdx.x, lane = t & 63, w = t >> 6;

  // staging: waves 0,1 -> A rows 0..63; waves 2,3 -> B rows 0..63 (rows 512 B; 128 B/step)
  const bool isB = (w >= 2);
  const char* panel = (isB ? (const char*)Tp : (const char*)Ep) + (size_t)p * (K * 512) +
                      (size_t)(isB ? b0 : a0) * 512;
  const int wrow0 = (w & 1) * 32;
  const int lrow = lane >> 3, lcol = (lane & 7) << 4;
  const int dofs = isB ? 8 * 1024 : 0;

  auto stage = [&](char* buf, int ks) {
    char* dst = buf + dofs;
#pragma unroll
    for (int i = 0; i < 4; ++i) {
      const int row = wrow0 + i * 8 + lrow;
      gload16(panel + (size_t)row * 512 + ks * 128 + (lcol ^ ((row & 7) << 4)),
              dst + row * 128 + lcol);
    }
  };

  const float pwp = pwv[p];  // uniform s_load, no vmcnt traffic

  stage(Buf[0], 0);  // prologue: 4 loads in flight per wave

  // compute geometry: wave w owns 32x32 quadrant (qr, qc); 2x2 frags of 16x16
  const int qr = (w >> 1) * 32, qc = (w & 1) * 32;
  const int l15 = lane & 15, hi16 = (lane >> 4) * 16;
  const int rsw = (l15 & 7) << 4;

  f32x4 acc00 = {0.f, 0.f, 0.f, 0.f}, acc01 = acc00, acc10 = acc00, acc11 = acc00;

#pragma unroll
  for (int ks = 0; ks < 4; ++ks) {
    const int cur = ks & 1;
    if (ks < 3) {
      stage(Buf[cur ^ 1], ks + 1);                      // 4 more in flight
      asm volatile("s_waitcnt vmcnt(4)" ::: "memory");  // current buf's 4 done
    } else {
      asm volatile("s_waitcnt vmcnt(0)" ::: "memory");
    }
    __builtin_amdgcn_s_barrier();
    __builtin_amdgcn_sched_barrier(0);
    const char* Ar0 = Buf[cur] + (size_t)(qr + l15) * 128;
    const char* Ar1 = Buf[cur] + (size_t)(qr + 16 + l15) * 128;
    const char* Br0 = Buf[cur] + 8 * 1024 + (size_t)(qc + l15) * 128;
    const char* Br1 = Buf[cur] + 8 * 1024 + (size_t)(qc + 16 + l15) * 128;
    __builtin_amdgcn_s_setprio(1);
#pragma unroll
    for (int kk = 0; kk < 2; ++kk) {
      const int off = (kk * 64 + hi16) ^ rsw;
      bf16x8 af0 = *(const bf16x8*)(Ar0 + off);
      bf16x8 af1 = *(const bf16x8*)(Ar1 + off);
      bf16x8 bf0 = *(const bf16x8*)(Br0 + off);
      bf16x8 bf1 = *(const bf16x8*)(Br1 + off);
      acc00 = __builtin_amdgcn_mfma_f32_16x16x32_bf16(af0, bf0, acc00, 0, 0, 0);
      acc01 = __builtin_amdgcn_mfma_f32_16x16x32_bf16(af0, bf1, acc01, 0, 0, 0);
      acc10 = __builtin_amdgcn_mfma_f32_16x16x32_bf16(af1, bf0, acc10, 0, 0, 0);
      acc11 = __builtin_amdgcn_mfma_f32_16x16x32_bf16(af1, bf1, acc11, 0, 0, 0);
    }
    __builtin_amdgcn_s_setprio(0);
    __builtin_amdgcn_s_barrier();  // reads of Buf[cur] done before it is re-staged
    __builtin_amdgcn_sched_barrier(0);
  }

  // epilogue: F(s) via L2 LUT (8 KB, hot), weighted, non-atomic write to p's plane
  float* pp = part + (size_t)p * NOUT;
  const int ar = a0 + qr + (lane >> 4) * 4;
  const int bc = b0 + qc + l15;
#pragma unroll
  for (int j = 0; j < 4; ++j) {
    float sv[4] = {acc00[j], acc01[j], acc10[j], acc11[j]};
    int id4[4] = {(ar + j) * K + bc, (ar + j) * K + bc + 16,
                  (ar + 16 + j) * K + bc, (ar + 16 + j) * K + bc + 16};
#pragma unroll
    for (int q = 0; q < 4; ++q) {
      float s = sv[q];
      float u = fminf(fmaxf((s + 1.0f) * (LN / 2), 0.0f), (float)LN);
      int i = min((int)u, LN - 1);
      float lt0 = tab[i], lt1 = tab[i + 1];
      float F = fmaf(u - (float)i, lt1 - lt0, lt0);
      pp[id4[q]] = F * pwp;
      if (s == 0.0f) atomicAdd(&corr[id4[q]], pwp);  // never taken on real data
    }
  }
}

// ---- finalize: reduce 40 p planes, divide ----
__global__ __launch_bounds__(256) void kdiv(const float* __restrict__ part,
                                            const float* __restrict__ corr,
                                            const float* __restrict__ pwv,
                                            float* __restrict__ out) {
  int gi = blockIdx.x * 256 + threadIdx.x;
  float s = 0.f;
#pragma unroll
  for (int p = 0; p < P; ++p) s += part[(size_t)p * NOUT + gi];
  out[gi] = s / (pwv[P] - corr[gi] + 1e-6f);
}

// ---- emergency fallback (no workspace needed) ----
__global__ __launch_bounds__(256) void kmono(const float* __restrict__ enroll,
                                             const float* __restrict__ test,
                                             const float* __restrict__ pho_w,
                                             const float* __restrict__ fc1w,
                                             const float* __restrict__ fc1b,
                                             const float* __restrict__ fc2w,
                                             float* __restrict__ out) {
  __shared__ float w1[C], b1[C], w2[C], pwm[P];
  const int t = threadIdx.x;
  if (t < C) {
    w1[t] = fc1w[t];
    b1[t] = fc1b[t];
    w2[t] = fc2w[t];
  }
  if (t < P) {
    float wmin = pho_w[0], wmax = pho_w[0];
    for (int i = 1; i < P; ++i) {
      float v = pho_w[i];
      wmin = fminf(wmin, v);
      wmax = fmaxf(wmax, v);
    }
    pwm[t] = (pho_w[t] - wmin) / (1e-6f + wmax - wmin);
  }
  __syncthreads();
  const int idx = blockIdx.x * 256 + t;
  const int a = idx >> 8, b = idx & 255;
  float score = 0.f, nz = 0.f;
  for (int p = 0; p < P; ++p) {
    float se = 0.f, st = 0.f, dot = 0.f;
    for (int d = 0; d < D; ++d) {
      float ev = enroll[((size_t)a * D + d) * P + p];
      float tv = test[((size_t)b * D + d) * P + p];
      se = fmaf(ev, ev, se);
      st = fmaf(tv, tv, st);
      dot = fmaf(ev, tv, dot);
    }
    float s = dot * (1.0f / fmaxf(sqrtf(se), 1e-12f)) * (1.0f / fmaxf(sqrtf(st), 1e-12f));
    float g = 0.f;
#pragma unroll
    for (int c = 0; c < C; ++c) g = fmaf(tanh_fast(fmaf(s, w1[c], b1[c])), w2[c], g);
    float f = tanh_fast(g * s);
    score = fmaf(f, pwm[p], score);
    if (s != 0.0f) nz += pwm[p];
  }
  out[idx] = score / (nz + 1e-6f);
}

}  // namespace

extern "C" void kernel_launch(void* const* d_in, const int* in_sizes, int n_in,
                              void* d_out, int out_size, void* d_ws, size_t ws_size,
                              hipStream_t stream) {
  const float* enroll = (const float*)d_in[0];
  const float* test = (const float*)d_in[1];
  const float* pho_w = (const float*)d_in[2];
  const float* fc1w = (const float*)d_in[3];
  const float* fc1b = (const float*)d_in[4];
  const float* fc2w = (const float*)d_in[5];
  float* out = (float*)d_out;

  const size_t np_pair = (size_t)P * K * 256;  // elements (bf16) per panel set
  const size_t need = 2 * np_pair * sizeof(unsigned short) +
                      (size_t)P * NOUT * sizeof(float) + (size_t)NOUT * sizeof(float) +
                      (size_t)(LN + 8) * sizeof(float) + (size_t)(P + 1) * sizeof(float);
  if (ws_size >= need) {
    unsigned short* Ep = (unsigned short*)d_ws;
    unsigned short* Tp = Ep + np_pair;
    float* part = (float*)(Tp + np_pair);   // [40][NOUT]
    float* corr = part + (size_t)P * NOUT;  // [NOUT]
    float* tab = corr + NOUT;
    float* pwv = tab + (LN + 4);

    kprep<<<2 * K + LB + CZB + 1, 256, 0, stream>>>(enroll, test, fc1w, fc1b, fc2w, pho_w,
                                                    Ep, Tp, tab, corr, pwv);
    kgemm<<<16 * P, 256, 0, stream>>>(Ep, Tp, tab, pwv, part, corr);
    kdiv<<<NOUT / 256, 256, 0, stream>>>(part, corr, pwv, out);
  } else {
    kmono<<<(K * K) / 256, 256, 0, stream>>>(enroll, test, pho_w, fc1w, fc1b, fc2w, out);
  }
}